// Round 18
// baseline (387.575 us; speedup 1.0000x reference)
//
#include <hip/hip_runtime.h>
#include <math.h>

#define QLEN 1024
#define BSZ 4
#define NH 10
#define DH 38
#define DM 380
#define DI 900
#define H3 1140
#define RLEN 2049
#define RLP 2112                      // RLEN padded to 33*64 (rk rows)
#define RLD 2052                      // BD row stride (10B entries, dword-aligned rows)
#define SCALE 0.16222142113076254f   // 1/sqrt(38)

typedef unsigned short ushortt;
typedef unsigned char uchar;
typedef __attribute__((ext_vector_type(8))) short short8;
typedef __attribute__((ext_vector_type(4))) float float4v;

__device__ __forceinline__ float bf2f(ushortt u) {
    return __uint_as_float(((unsigned int)u) << 16);
}
__device__ __forceinline__ ushortt f2bf(float f) {
    unsigned int u = __float_as_uint(f);
    u += 0x7fffu + ((u >> 16) & 1u);   // RNE
    return (ushortt)(u >> 16);
}
// ---- fp8 e4m3fn codec (flush subnormals; saturate to 448) ----
__device__ __forceinline__ uchar f2e4m3(float f) {
    unsigned u = __float_as_uint(f);
    unsigned s = (u >> 24) & 0x80u;
    unsigned b = u & 0x7fffffffu;
    b += 0x7FFFFu + ((b >> 20) & 1u);          // RNE to 3 mantissa bits
    int E = (int)(b >> 23) - 120;              // e4m3 exponent field
    if (E <= 0) return (uchar)s;               // underflow -> 0
    if (E > 15 || (E == 15 && ((b >> 20) & 7u) > 6u)) return (uchar)(s | 0x7Eu);
    return (uchar)(s | ((unsigned)E << 3) | ((b >> 20) & 7u));
}
__device__ __forceinline__ float e4m32f(uchar v) {
    unsigned s = ((unsigned)(v & 0x80u)) << 24;
    int E = (v >> 3) & 15; unsigned m = v & 7u;
    if (E == 0) return __uint_as_float(s);     // flush
    return __uint_as_float(s | ((unsigned)(E + 120) << 23) | (m << 20));
}

__device__ __forceinline__ void convseg(const float* src, ushortt* dst,
                                        int R, int C, int Rp, int Cp,
                                        int tid0, int stride) {
    const int total = Rp * Cp;
    for (int i = tid0; i < total; i += stride) {
        int r = i / Cp, c = i - r * Cp;
        float v = (r < R && c < C) ? src[(size_t)r * C + c] : 0.f;
        dst[i] = f2bf(v);
    }
}

// ---------- one fused prologue: all conversions + all pad zeroing ----------
__global__ __launch_bounds__(256)
void prep_all(const float* __restrict__ w,    ushortt* __restrict__ w_bf,
              const float* __restrict__ qkv,  ushortt* __restrict__ qkv_bf,
              const float* __restrict__ r,    ushortt* __restrict__ r_bf,
              const float* __restrict__ rw,   ushortt* __restrict__ rw_bf,
              const float* __restrict__ ow,   ushortt* __restrict__ ow_bf,
              const float* __restrict__ f1,   ushortt* __restrict__ f1_bf,
              const float* __restrict__ f2,   ushortt* __restrict__ f2_bf,
              ushortt* __restrict__ qw_bf, ushortt* __restrict__ Kb, ushortt* __restrict__ Vb,
              ushortt* __restrict__ qr_bf, ushortt* __restrict__ rk_bf,
              ushortt* __restrict__ vec) {
    const int stride = gridDim.x * 256;
    const int tid0 = blockIdx.x * 256 + threadIdx.x;
    convseg(w,   w_bf,   4096, DM, 4096, 384, tid0, stride);
    convseg(qkv, qkv_bf, H3,   DM, 1152, 384, tid0, stride);
    convseg(r,   r_bf,   RLEN, DM, 2176, 384, tid0, stride);
    convseg(rw,  rw_bf,  DM,   DM, 384,  384, tid0, stride);
    convseg(ow,  ow_bf,  DM,   DM, 384,  384, tid0, stride);
    convseg(f1,  f1_bf,  DI,   DM, 960,  384, tid0, stride);
    convseg(f2,  f2_bf,  DM,   DI, 384,  928, tid0, stride);
    for (int i = tid0; i < BSZ * NH * 1024 * 2; i += stride) {     // d=38,39 pads (qw/K/V)
        size_t idx = (size_t)(i >> 1) * 40 + 38 + (i & 1);
        qw_bf[idx] = 0; Kb[idx] = 0; Vb[idx] = 0;
    }
    for (int i = tid0; i < 4096 * 4; i += stride)                  // vec cols 380..383
        vec[(size_t)(i >> 2) * 384 + 380 + (i & 3)] = 0;
    for (int i = tid0; i < BSZ * NH * 1024 * 26; i += stride) {    // qr cols 38..63
        int row = i / 26, c = 38 + i % 26;
        qr_bf[(size_t)row * 64 + c] = 0;
    }
    for (int i = tid0; i < NH * RLP * 26; i += stride) {           // rk cols 38..63
        int row = i / 26, c = 38 + i % 26;
        rk_bf[(size_t)row * 64 + c] = 0;
    }
    for (int i = tid0; i < NH * 63 * 64; i += stride) {            // rk rows 2049..2111
        int n = i / (63 * 64), rem = i % (63 * 64);
        rk_bf[((size_t)n * RLP + RLEN + rem / 64) * 64 + rem % 64] = 0;
    }
}

// ---------------- bf16 MFMA GEMM:  C[M,N] = A[M,Kp] * B[N,Kp]^T ----------------
// EPI: 0 = f32 store, 3 = relu(x+bias)->bf16 (ld 928), 4 = x+bias->f32,
//      5 = QKV scatter (qw_bf bf16[40] + qr_bf bf16[64] + K_bf/V_bf bf16[40]),
//      6 = rk -> rk_bf bf16 [n][2112][64]
template<int EPI>
__global__ __launch_bounds__(256)
void gemm_mfma(const ushortt* __restrict__ A, const ushortt* __restrict__ B,
               const float* __restrict__ bias, void* __restrict__ Cout,
               int M, int N, int Kpp, int ldc,
               const float* __restrict__ bias2, float* __restrict__ out2,
               float* __restrict__ out3, float* __restrict__ out4) {
    __shared__ __align__(16) ushortt As[128 * 32];
    __shared__ __align__(16) ushortt Bs[64 * 32];
    const int tid = threadIdx.x;
    const int wid = tid >> 6, lane = tid & 63;
    const int bRow = blockIdx.y * 128, bCol = blockIdx.x * 64;

    float4v acc[2][4];
    const float4v zz = {0.f, 0.f, 0.f, 0.f};
    #pragma unroll
    for (int m = 0; m < 2; ++m)
        #pragma unroll
        for (int n = 0; n < 4; ++n) acc[m][n] = zz;

    const int arow = tid >> 1, acol = (tid & 1) * 16;
    const int brow = tid >> 2, bcol = (tid & 3) * 8;
    const int fr = lane & 15, kg = lane >> 4;

    for (int k0 = 0; k0 < Kpp; k0 += 32) {
        const ushortt* ag = A + (size_t)(bRow + arow) * Kpp + k0 + acol;
        float4v a0 = *(const float4v*)ag;
        float4v a1 = *(const float4v*)(ag + 8);
        const ushortt* bg = B + (size_t)(bCol + brow) * Kpp + k0 + bcol;
        float4v b0 = *(const float4v*)bg;
        __syncthreads();
        *(float4v*)&As[arow * 32 + acol] = a0;
        *(float4v*)&As[arow * 32 + acol + 8] = a1;
        *(float4v*)&Bs[brow * 32 + bcol] = b0;
        __syncthreads();

        short8 bf[4];
        #pragma unroll
        for (int n = 0; n < 4; ++n)
            bf[n] = *(const short8*)&Bs[(n * 16 + fr) * 32 + kg * 8];
        #pragma unroll
        for (int m = 0; m < 2; ++m) {
            short8 af = *(const short8*)&As[(wid * 32 + m * 16 + fr) * 32 + kg * 8];
            #pragma unroll
            for (int n = 0; n < 4; ++n)
                acc[m][n] = __builtin_amdgcn_mfma_f32_16x16x32_bf16(af, bf[n], acc[m][n], 0, 0, 0);
        }
    }

    #pragma unroll
    for (int m = 0; m < 2; ++m)
        #pragma unroll
        for (int n = 0; n < 4; ++n)
            #pragma unroll
            for (int j = 0; j < 4; ++j) {
                const int row = bRow + wid * 32 + m * 16 + (lane >> 4) * 4 + j;
                const int col = bCol + n * 16 + (lane & 15);
                const float v = acc[m][n][j];
                if (EPI == 0) {
                    if (row < M && col < N) ((float*)Cout)[(size_t)row * ldc + col] = v;
                } else if (EPI == 3) {
                    if (row < M && col < 928) {
                        float h = (col < DI) ? fmaxf(v + bias[col], 0.f) : 0.f;
                        ((ushortt*)Cout)[(size_t)row * 928 + col] = f2bf(h);
                    }
                } else if (EPI == 4) {
                    if (row < M && col < N) ((float*)Cout)[(size_t)row * ldc + col] = v + bias[col];
                } else if (EPI == 5) {
                    if (col < H3) {
                        int part = col / 380;
                        int c = col - part * 380;
                        int nh = c / 38, d = c - nh * 38;
                        int q = row >> 2, b2 = row & 3;
                        size_t i40 = (((size_t)b2 * NH + nh) * 1024 + q) * 40 + d;
                        size_t i64 = (((size_t)b2 * NH + nh) * 1024 + q) * 64 + d;
                        if (part == 0) {
                            ((ushortt*)Cout)[i40] = f2bf(v + bias[c]);         // qw_bf (+r_w_bias)
                            ((ushortt*)out2)[i64] = f2bf(v + bias2[c]);        // qr_bf (+r_r_bias)
                        } else if (part == 1) ((ushortt*)out3)[i40] = f2bf(v); // K_bf
                        else ((ushortt*)out4)[i40] = f2bf(v);                  // V_bf
                    }
                } else {  // EPI 6
                    if (row < RLEN && col < DM) {
                        int nh = col / 38, d = col - nh * 38;
                        ((ushortt*)Cout)[((size_t)nh * RLP + row) * 64 + d] = f2bf(v);
                    }
                }
            }
}

// ---------------- BD GEMM: all 10 heads per block, fp8 out, coalesced store -----
// BD: fp8 [lb][1024 q][2052 j][10 n]; 1-D XCD-grouped grid (65 jt share A-panel).
__global__ __launch_bounds__(256)
void bd_gemm(const ushortt* __restrict__ qr, const ushortt* __restrict__ rk,
             uchar* __restrict__ BD, int bofs, int nb) {
    __shared__ __align__(16) ushortt As[64][72];
    __shared__ __align__(16) ushortt Bs[32][72];
    __shared__ __align__(16) uchar Call[64 * 32 * 10];
    const int bid = blockIdx.x;
    const int xcd = bid & 7, t = bid >> 3;
    const int gl = t / 65, jt = t - gl * 65;
    const int G = gl * 8 + xcd;             // 0 .. 16*nb-1
    const int lb = G >> 4, qt = G & 15;
    const int tid = threadIdx.x;
    const int wid = tid >> 6, lane = tid & 63;
    const int j0 = jt * 32, q0 = qt * 64;
    const int fr = lane & 15, kg = lane >> 4;
    const int jcount = min(32, RLEN - j0);

    for (int n = 0; n < NH; ++n) {
        const ushortt* Ab = qr + (((size_t)(bofs + lb) * NH + n) * 1024 + q0) * 64;
        const ushortt* Bb = rk + ((size_t)n * RLP + j0) * 64;
        __syncthreads();
        {
            int rr = tid >> 2, cc = (tid & 3) * 16;
            *(float4v*)&As[rr][cc] = *(const float4v*)(Ab + (size_t)rr * 64 + cc);
            *(float4v*)&As[rr][cc + 8] = *(const float4v*)(Ab + (size_t)rr * 64 + cc + 8);
            int br = tid >> 3, bc = (tid & 7) * 8;
            *(float4v*)&Bs[br][bc] = *(const float4v*)(Bb + (size_t)br * 64 + bc);
        }
        __syncthreads();
        float4v acc[2] = {{0.f,0.f,0.f,0.f},{0.f,0.f,0.f,0.f}};
        #pragma unroll
        for (int ks = 0; ks < 64; ks += 32) {
            short8 af = *(const short8*)&As[wid * 16 + fr][ks + kg * 8];
            #pragma unroll
            for (int c = 0; c < 2; ++c) {
                short8 bfr = *(const short8*)&Bs[c * 16 + fr][ks + kg * 8];
                acc[c] = __builtin_amdgcn_mfma_f32_16x16x32_bf16(af, bfr, acc[c], 0, 0, 0);
            }
        }
        #pragma unroll
        for (int c = 0; c < 2; ++c)
            #pragma unroll
            for (int jj = 0; jj < 4; ++jj) {
                int rq = wid * 16 + (lane >> 4) * 4 + jj;
                int cj = c * 16 + (lane & 15);
                Call[(rq * 32 + cj) * 10 + n] = f2e4m3(acc[c][jj]);
            }
    }
    __syncthreads();
    if (jcount == 32) {
        const unsigned* Cdw = (const unsigned*)Call;
        unsigned* G2 = (unsigned*)BD;
        for (int idx = tid; idx < 64 * 80; idx += 256) {
            int rr = idx / 80, rem = idx - rr * 80;
            size_t gdw = (((size_t)(lb * 1024 + q0 + rr) * RLD + j0) * 10) >> 2;
            G2[gdw + rem] = Cdw[rr * 80 + rem];
        }
    } else {  // tail tile (j0=2048, jcount=1): 10 bytes per row
        for (int idx = tid; idx < 64 * 10; idx += 256) {
            int rr = idx / 10, n2 = idx - rr * 10;
            BD[((size_t)(lb * 1024 + q0 + rr) * RLD + j0) * 10 + n2] = Call[rr * 320 + n2];
        }
    }
}

// ---------------- MFMA-AC split-K fused attention, 64 q-rows per block -------
// qw_bf/K_bf/V_bf bf16 [b][n][1024][40]; BD fp8 [lb][1024 q][2052 j][10]
// QBLK=64: halves K/V staging traffic. LDS 25.9KB -> 6 blocks/CU.
// 4 lanes/row, 16 k-slots/thread. ntiles = qc+1 (qc 0..15); ns = (qc>>2)+1.
__global__ __launch_bounds__(256)
void attn8(const ushortt* __restrict__ qwb, const ushortt* __restrict__ Kp,
           const ushortt* __restrict__ Vp, const uchar* __restrict__ BD,
           const int* __restrict__ relpos,
           ushortt* __restrict__ op, float2* __restrict__ ml, int b0, int nb) {
    const int bid = blockIdx.x;
    const int xcd = bid & 7, t = bid >> 3;
    const int gl = t / 10, n = t - gl * 10;
    const int G = gl * 8 + xcd;                // 0 .. 40*nb-1, heavy-first
    int qc, lb, s;
    {
        const int c4 = 16 * nb, c3 = 12 * nb, c2 = 8 * nb;
        if (G < c4)                { qc = 15 - G / (4 * nb); int r2 = G % (4 * nb); lb = r2 >> 2; s = r2 & 3; }
        else if (G < c4 + c3)      { int g2 = G - c4; qc = 11 - g2 / (3 * nb); int r2 = g2 % (3 * nb); lb = r2 / 3; s = r2 % 3; }
        else if (G < c4 + c3 + c2) { int g2 = G - c4 - c3; qc = 7 - g2 / (2 * nb); int r2 = g2 % (2 * nb); lb = r2 >> 1; s = r2 & 1; }
        else                       { int g2 = G - c4 - c3 - c2; qc = 3 - g2 / nb; lb = g2 % nb; s = 0; }
    }
    const int ns = (qc >> 2) + 1;
    const int ntiles = qc + 1;
    const int qbase = qc * 64;
    const int b = b0 + lb;
    const int tid = threadIdx.x;
    const int wid = tid >> 6, lane = tid & 63;
    const int row = tid >> 2, kg = tid & 3;    // 64 rows, 4 lanes/row
    const int qi = qbase + row;
    const size_t bn = (size_t)b * NH + n;
    const size_t prow = ((size_t)s * (BSZ * NH) + bn) * 1024 + qi;

    __shared__ __align__(16) ushortt KtL[64 * 48];
    __shared__ __align__(16) ushortt VtL[64 * 40];
    __shared__ __align__(16) ushortt qwL[64 * 48];
    __shared__ __align__(16) ushortt sL[64 * 66];

    const ushortt* Kbase = Kp + bn * 1024 * 40;
    const ushortt* Vbase = Vp + bn * 1024 * 40;
    const int fr = lane & 15;
    const int kg8 = (lane >> 4) * 8;
    const bool kgz = (lane >> 4) == 0;
    const short8 z8 = {0, 0, 0, 0, 0, 0, 0, 0};

    // block-start: stage qwL (64 x 40 bf16, stride 48)
    for (int e = tid; e < 320; e += 256) {
        int rr = e / 5, cc = (e % 5) * 8;
        *(short8*)&qwL[rr * 48 + cc] = *(const short8*)(qwb + (bn * 1024 + qbase + rr) * 40 + cc);
    }
    float o[10];
    #pragma unroll
    for (int i = 0; i < 10; ++i) o[i] = 0.f;
    float mrun = -INFINITY, lrun = 0.f;
    const int* rp = relpos + ((size_t)b * QLEN + qi) * QLEN;
    const uchar* bdrow = BD + ((size_t)(lb * 1024 + qi)) * (RLD * 10) + n;

    for (int kt = s; kt < ntiles; kt += ns) {
        const int k0 = kt * 64;
        __syncthreads();
        // stage K (stride 48) + V (stride 40), raw bf16
        for (int e = tid; e < 320; e += 256) {
            int rr = e / 5, cc = (e % 5) * 8;
            *(short8*)&KtL[rr * 48 + cc] = *(const short8*)(Kbase + (size_t)(k0 + rr) * 40 + cc);
        }
        for (int e = tid; e < 320; e += 256)
            ((short8*)VtL)[e] = ((const short8*)(Vbase + (size_t)k0 * 40))[e];
        __syncthreads();

        // BD gather: 16 slots/thread (k = kg + ss*4), issued before MFMA
        float bdv[16];
        unsigned vmask = 0;
        #pragma unroll
        for (int ss = 0; ss < 16; ++ss) {
            const int kk = k0 + kg + ss * 4;
            float bv = 0.f;
            if (kk <= qi) {
                int rpv = rp[kk];
                rpv = rpv < -1024 ? -1024 : (rpv > 1024 ? 1024 : rpv);
                bv = e4m32f(bdrow[(size_t)(1024 - rpv) * 10]);
                vmask |= 1u << ss;
            }
            bdv[ss] = bv;
        }

        // MFMA: AC[64][64] = qw @ K^T  (wave wid -> row-tile mt=wid, 4 ct tiles)
        {
            const int mt = wid;
            short8 a0 = *(const short8*)&qwL[(mt * 16 + fr) * 48 + kg8];
            short8 a1 = kgz ? *(const short8*)&qwL[(mt * 16 + fr) * 48 + 32] : z8;
            #pragma unroll
            for (int ct = 0; ct < 4; ++ct) {
                short8 b0f = *(const short8*)&KtL[(ct * 16 + fr) * 48 + kg8];
                short8 b1f = kgz ? *(const short8*)&KtL[(ct * 16 + fr) * 48 + 32] : z8;
                float4v acc = {0.f, 0.f, 0.f, 0.f};
                acc = __builtin_amdgcn_mfma_f32_16x16x32_bf16(a0, b0f, acc, 0, 0, 0);
                acc = __builtin_amdgcn_mfma_f32_16x16x32_bf16(a1, b1f, acc, 0, 0, 0);
                #pragma unroll
                for (int j = 0; j < 4; ++j)
                    sL[(mt * 16 + (lane >> 4) * 4 + j) * 66 + ct * 16 + fr] = f2bf(acc[j]);
            }
        }
        __syncthreads();

        // score combine + online softmax (thread owns cells (row, kg+ss*4))
        ushortt* prw = sL + row * 66;
        float pmax = -INFINITY;
        #pragma unroll
        for (int ss = 0; ss < 16; ++ss) {
            const int k = kg + ss * 4;
            float sv = -INFINITY;
            if (vmask & (1u << ss))
                sv = (bf2f(prw[k]) + bdv[ss]) * SCALE;
            bdv[ss] = sv;                       // reuse as s-array
            pmax = fmaxf(pmax, sv);
        }
        pmax = fmaxf(pmax, __shfl_xor(pmax, 1, 64));
        pmax = fmaxf(pmax, __shfl_xor(pmax, 2, 64));
        const float nm = fmaxf(mrun, pmax);
        const float corr = __expf(mrun - nm);   // first tile: exp(-inf)=0
        float psum = 0.f;
        #pragma unroll
        for (int ss = 0; ss < 16; ++ss) {
            float p = __expf(bdv[ss] - nm);     // -inf -> 0
            psum += p;
            prw[kg + ss * 4] = f2bf(p);
        }
        psum += __shfl_xor(psum, 1, 64);
        psum += __shfl_xor(psum, 2, 64);
        lrun = lrun * corr + psum;
        mrun = nm;
        #pragma unroll
        for (int i = 0; i < 10; ++i) o[i] *= corr;
        int kmax = qi - k0 + 1; if (kmax > 64) kmax = 64;
        #pragma unroll 4
        for (int k = 0; k < kmax; ++k) {
            float p = bf2f(prw[k]);
            const unsigned* vp = (const unsigned*)(VtL + k * 40 + kg * 10);
            #pragma unroll
            for (int i = 0; i < 5; ++i) {
                unsigned u = vp[i];
                o[2 * i]     += p * bf2f((ushortt)(u & 0xffff));
                o[2 * i + 1] += p * bf2f((ushortt)(u >> 16));
            }
        }
    }
    ushortt* oprow = op + prow * 40 + kg * 10;
    #pragma unroll
    for (int i = 0; i < 10; ++i) oprow[i] = f2bf(o[i]);
    if (kg == 0) ml[prow] = make_float2(mrun, lrun);
}

// ---------------- combine split partials -> vec (bf16) ----------------
__global__ __launch_bounds__(256)
void attn_combine(const ushortt* __restrict__ op, const float2* __restrict__ ml,
                  ushortt* __restrict__ vec) {
    const int idx = blockIdx.x * 256 + threadIdx.x;
    if (idx >= BSZ * NH * 1024 * 38) return;
    const int d = idx % 38;
    const int rh = idx / 38;                 // bn*1024 + q
    const int q = rh & 1023;
    const int bn = rh >> 10;
    const int b = bn / NH, n = bn - b * NH;
    const int ns = ((q >> 6) >> 2) + 1;      // splits for this q's 64-chunk
    const size_t stride = (size_t)BSZ * NH * 1024;
    float M = -INFINITY;
    float2 mv[4];
    for (int sp = 0; sp < ns; ++sp) {
        mv[sp] = ml[sp * stride + rh];
        M = fmaxf(M, mv[sp].x);
    }
    float l = 0.f, o = 0.f;
    for (int sp = 0; sp < ns; ++sp) {
        float w = __expf(mv[sp].x - M);
        l += mv[sp].y * w;
        o += bf2f(op[(sp * stride + rh) * 40 + d]) * w;
    }
    vec[((size_t)q * BSZ + b) * 384 + (size_t)n * 38 + d] = f2bf(o / l);
}

// ---------------- residual + LayerNorm ----------------
template<bool WRITE_BF>
__global__ __launch_bounds__(256)
void ln_kernel(const float* __restrict__ x1, const float* __restrict__ x2,
               const float* __restrict__ g, const float* __restrict__ bb,
               float* __restrict__ outf, ushortt* __restrict__ outbf) {
    const int row = blockIdx.x;
    const float* p1 = x1 + (size_t)row * DM;
    const float* p2 = x2 + (size_t)row * DM;
    __shared__ float xb[DM];
    __shared__ float red[256];
    const int tid = threadIdx.x;
    float s = 0.f;
    for (int i = tid; i < DM; i += 256) { float v = p1[i] + p2[i]; xb[i] = v; s += v; }
    red[tid] = s; __syncthreads();
    for (int st = 128; st > 0; st >>= 1) { if (tid < st) red[tid] += red[tid + st]; __syncthreads(); }
    const float mean = red[0] / DM;
    __syncthreads();
    float s2 = 0.f;
    for (int i = tid; i < DM; i += 256) { float d = xb[i] - mean; s2 += d * d; }
    red[tid] = s2; __syncthreads();
    for (int st = 128; st > 0; st >>= 1) { if (tid < st) red[tid] += red[tid + st]; __syncthreads(); }
    const float rstd = rsqrtf(red[0] / DM + 1e-5f);
    for (int i = tid; i < (WRITE_BF ? 384 : DM); i += 256) {
        float v = 0.f;
        if (i < DM) {
            v = (xb[i] - mean) * rstd * g[i] + bb[i];
            outf[(size_t)row * DM + i] = v;
        }
        if (WRITE_BF) outbf[(size_t)row * 384 + i] = f2bf(i < DM ? v : 0.f);
    }
}

extern "C" void kernel_launch(void* const* d_in, const int* in_sizes, int n_in,
                              void* d_out, int out_size, void* d_ws, size_t ws_size,
                              hipStream_t stream) {
    const float* w     = (const float*)d_in[0];
    const float* r     = (const float*)d_in[1];
    const float* rwb   = (const float*)d_in[2];
    const float* rrb   = (const float*)d_in[3];
    const float* qkv_w = (const float*)d_in[4];
    const float* r_w   = (const float*)d_in[5];
    const float* o_w   = (const float*)d_in[6];
    const float* ln1g  = (const float*)d_in[7];
    const float* ln1b  = (const float*)d_in[8];
    const float* ffw1  = (const float*)d_in[9];
    const float* ffb1  = (const float*)d_in[10];
    const float* ffw2  = (const float*)d_in[11];
    const float* ffb2  = (const float*)d_in[12];
    const float* ln2g  = (const float*)d_in[13];
    const float* ln2b  = (const float*)d_in[14];
    const int*   relpos = (const int*)d_in[16];
    float* out = (float*)d_out;

    char* cur = (char*)d_ws;
    auto alloc = [&](size_t bytes) { char* p = cur; cur += (bytes + 255) & ~(size_t)255; return p; };
    ushortt* w_bf    = (ushortt*)alloc((size_t)4096 * 384 * 2);
    ushortt* qkv_bf  = (ushortt*)alloc((size_t)1152 * 384 * 2);
    ushortt* r_bf    = (ushortt*)alloc((size_t)2176 * 384 * 2);
    ushortt* rw_bf   = (ushortt*)alloc((size_t)384 * 384 * 2);
    ushortt* ow_bf   = (ushortt*)alloc((size_t)384 * 384 * 2);
    ushortt* f1_bf   = (ushortt*)alloc((size_t)960 * 384 * 2);
    ushortt* f2_bf   = (ushortt*)alloc((size_t)384 * 928 * 2);
    ushortt* qw_bf   = (ushortt*)alloc((size_t)BSZ * NH * 1024 * 40 * 2);
    ushortt* K_bf    = (ushortt*)alloc((size_t)BSZ * NH * 1024 * 40 * 2);
    ushortt* V_bf    = (ushortt*)alloc((size_t)BSZ * NH * 1024 * 40 * 2);
    ushortt* qr_bf   = (ushortt*)alloc((size_t)BSZ * NH * 1024 * 64 * 2);
    ushortt* rk_bf   = (ushortt*)alloc((size_t)NH * RLP * 64 * 2);
    ushortt* vec_bf  = (ushortt*)alloc((size_t)4096 * 384 * 2);
    ushortt* out1_bf = (ushortt*)alloc((size_t)4096 * 384 * 2);
    ushortt* h1_bf   = (ushortt*)alloc((size_t)4096 * 928 * 2);
    float*   attnf   = (float*)alloc((size_t)4096 * DM * 4);
    float*   out1f   = (float*)alloc((size_t)4096 * DM * 4);
    float*   core    = (float*)alloc((size_t)4096 * DM * 4);

    // split partials alias attnf/out1f/core (dead until after combine):
    ushortt* op_part = (ushortt*)attnf;
    float2*  ml_part = (float2*)((char*)attnf + (size_t)4 * BSZ * NH * 1024 * 40 * 2);

    // BD buffer: fp8 [lb][1024 q][2052 j][10]
    const size_t bd_b_bytes = (size_t)1024 * RLD * 10;   // per-b: ~21 MB
    uchar* BD = (uchar*)alloc(bd_b_bytes * BSZ);
    bool full = ((size_t)(cur - (char*)d_ws) <= ws_size);
    if (!full) { cur = (char*)BD; BD = (uchar*)alloc(bd_b_bytes); }  // per-b reuse

    auto cgrid = [](size_t total) { return dim3((unsigned)((total + 255) / 256)); };
    // fused prologue: all conversions + all pad zeroing, one launch
    prep_all<<<dim3(2048), 256, 0, stream>>>(w, w_bf, qkv_w, qkv_bf, r, r_bf,
                                             r_w, rw_bf, o_w, ow_bf, ffw1, f1_bf, ffw2, f2_bf,
                                             qw_bf, K_bf, V_bf, qr_bf, rk_bf, vec_bf);

    // QKV GEMM with scatter epilogue -> qw_bf / qr_bf / K_bf / V_bf
    gemm_mfma<5><<<dim3(18, 32), 256, 0, stream>>>(w_bf, qkv_bf, rwb, qw_bf, 4096, H3, 384, 0,
                                                   rrb, (float*)qr_bf, (float*)K_bf, (float*)V_bf);
    // rk GEMM -> rk_bf  bf16 [n][2112][64]
    gemm_mfma<6><<<dim3(6, 17), 256, 0, stream>>>(r_bf, rw_bf, nullptr, rk_bf, RLEN, DM, 384, 0,
                                                  nullptr, nullptr, nullptr, nullptr);
    if (full) {
        bd_gemm<<<dim3(65 * 16 * BSZ), 256, 0, stream>>>(qr_bf, rk_bf, BD, 0, BSZ);
        attn8<<<dim3(1600), 256, 0, stream>>>(qw_bf, K_bf, V_bf, BD, relpos,
                                              op_part, ml_part, 0, BSZ);
    } else {
        for (int b = 0; b < BSZ; ++b) {
            bd_gemm<<<dim3(65 * 16), 256, 0, stream>>>(qr_bf, rk_bf, BD, b, 1);
            attn8<<<dim3(400), 256, 0, stream>>>(qw_bf, K_bf, V_bf, BD, relpos,
                                                 op_part, ml_part, b, 1);
        }
    }
    attn_combine<<<cgrid((size_t)BSZ * NH * 1024 * 38), 256, 0, stream>>>(op_part, ml_part, vec_bf);
    // attn_out = vec @ o_w^T   (overwrites op_part alias -- partials are dead)
    gemm_mfma<0><<<dim3(6, 32), 256, 0, stream>>>(vec_bf, ow_bf, nullptr, attnf, 4096, DM, 384, DM,
                                                  nullptr, nullptr, nullptr, nullptr);
    ln_kernel<true><<<4096, 256, 0, stream>>>(w, attnf, ln1g, ln1b, out1f, out1_bf);
    gemm_mfma<3><<<dim3(15, 32), 256, 0, stream>>>(out1_bf, f1_bf, ffb1, h1_bf, 4096, DI, 384, 928,
                                                   nullptr, nullptr, nullptr, nullptr);
    gemm_mfma<4><<<dim3(6, 32), 256, 0, stream>>>(h1_bf, f2_bf, ffb2, core, 4096, DM, 928, DM,
                                                  nullptr, nullptr, nullptr, nullptr);
    ln_kernel<false><<<4096, 256, 0, stream>>>(out1f, core, ln2g, ln2b, out, nullptr);
}

// Round 21
// 352.387 us; speedup vs baseline: 1.0999x; 1.0999x over previous
//
#include <hip/hip_runtime.h>
#include <math.h>

#define QLEN 1024
#define BSZ 4
#define NH 10
#define DH 38
#define DM 380
#define DI 900
#define H3 1140
#define RLEN 2049
#define RLP 2112                      // RLEN padded to 33*64 (rk rows)
#define RLD 2052                      // BD row stride (10B entries, dword-aligned rows)
#define SCALE 0.16222142113076254f   // 1/sqrt(38)

typedef unsigned short ushortt;
typedef unsigned char uchar;
typedef __attribute__((ext_vector_type(8))) short short8;
typedef __attribute__((ext_vector_type(4))) float float4v;

__device__ __forceinline__ float bf2f(ushortt u) {
    return __uint_as_float(((unsigned int)u) << 16);
}
__device__ __forceinline__ ushortt f2bf(float f) {
    unsigned int u = __float_as_uint(f);
    u += 0x7fffu + ((u >> 16) & 1u);   // RNE
    return (ushortt)(u >> 16);
}
// ---- fp8 e4m3fn codec (flush subnormals; saturate to 448) ----
__device__ __forceinline__ uchar f2e4m3(float f) {
    unsigned u = __float_as_uint(f);
    unsigned s = (u >> 24) & 0x80u;
    unsigned b = u & 0x7fffffffu;
    b += 0x7FFFFu + ((b >> 20) & 1u);          // RNE to 3 mantissa bits
    int E = (int)(b >> 23) - 120;              // e4m3 exponent field
    if (E <= 0) return (uchar)s;               // underflow -> 0
    if (E > 15 || (E == 15 && ((b >> 20) & 7u) > 6u)) return (uchar)(s | 0x7Eu);
    return (uchar)(s | ((unsigned)E << 3) | ((b >> 20) & 7u));
}
__device__ __forceinline__ float e4m32f(uchar v) {
    unsigned s = ((unsigned)(v & 0x80u)) << 24;
    int E = (v >> 3) & 15; unsigned m = v & 7u;
    if (E == 0) return __uint_as_float(s);     // flush
    return __uint_as_float(s | ((unsigned)(E + 120) << 23) | (m << 20));
}

__device__ __forceinline__ void convseg(const float* src, ushortt* dst,
                                        int R, int C, int Rp, int Cp,
                                        int tid0, int stride) {
    const int total = Rp * Cp;
    for (int i = tid0; i < total; i += stride) {
        int r = i / Cp, c = i - r * Cp;
        float v = (r < R && c < C) ? src[(size_t)r * C + c] : 0.f;
        dst[i] = f2bf(v);
    }
}

// ---------- one fused prologue: all conversions + all pad zeroing ----------
__global__ __launch_bounds__(256)
void prep_all(const float* __restrict__ w,    ushortt* __restrict__ w_bf,
              const float* __restrict__ qkv,  ushortt* __restrict__ qkv_bf,
              const float* __restrict__ r,    ushortt* __restrict__ r_bf,
              const float* __restrict__ rw,   ushortt* __restrict__ rw_bf,
              const float* __restrict__ ow,   ushortt* __restrict__ ow_bf,
              const float* __restrict__ f1,   ushortt* __restrict__ f1_bf,
              const float* __restrict__ f2,   ushortt* __restrict__ f2_bf,
              ushortt* __restrict__ qw_bf, ushortt* __restrict__ Kb, ushortt* __restrict__ Vb,
              ushortt* __restrict__ qr_bf, ushortt* __restrict__ rk_bf,
              ushortt* __restrict__ vec) {
    const int stride = gridDim.x * 256;
    const int tid0 = blockIdx.x * 256 + threadIdx.x;
    convseg(w,   w_bf,   4096, DM, 4096, 384, tid0, stride);
    convseg(qkv, qkv_bf, H3,   DM, 1152, 384, tid0, stride);
    convseg(r,   r_bf,   RLEN, DM, 2176, 384, tid0, stride);
    convseg(rw,  rw_bf,  DM,   DM, 384,  384, tid0, stride);
    convseg(ow,  ow_bf,  DM,   DM, 384,  384, tid0, stride);
    convseg(f1,  f1_bf,  DI,   DM, 960,  384, tid0, stride);
    convseg(f2,  f2_bf,  DM,   DI, 384,  928, tid0, stride);
    for (int i = tid0; i < BSZ * NH * 1024 * 2; i += stride) {     // d=38,39 pads (qw/K/V)
        size_t idx = (size_t)(i >> 1) * 40 + 38 + (i & 1);
        qw_bf[idx] = 0; Kb[idx] = 0; Vb[idx] = 0;
    }
    for (int i = tid0; i < 4096 * 4; i += stride)                  // vec cols 380..383
        vec[(size_t)(i >> 2) * 384 + 380 + (i & 3)] = 0;
    for (int i = tid0; i < BSZ * NH * 1024 * 26; i += stride) {    // qr cols 38..63
        int row = i / 26, c = 38 + i % 26;
        qr_bf[(size_t)row * 64 + c] = 0;
    }
    for (int i = tid0; i < NH * RLP * 26; i += stride) {           // rk cols 38..63
        int row = i / 26, c = 38 + i % 26;
        rk_bf[(size_t)row * 64 + c] = 0;
    }
    for (int i = tid0; i < NH * 63 * 64; i += stride) {            // rk rows 2049..2111
        int n = i / (63 * 64), rem = i % (63 * 64);
        rk_bf[((size_t)n * RLP + RLEN + rem / 64) * 64 + rem % 64] = 0;
    }
}

// ---------------- bf16 MFMA GEMM:  C[M,N] = A[M,Kp] * B[N,Kp]^T ----------------
// EPI: 0 = f32 store, 3 = relu(x+bias)->bf16 (ld 928), 4 = x+bias->f32,
//      5 = QKV scatter (qw_bf bf16[40] + qr_bf bf16[64] + K_bf/V_bf bf16[40]),
//      6 = rk -> rk_bf bf16 [n][2112][64]
template<int EPI>
__global__ __launch_bounds__(256)
void gemm_mfma(const ushortt* __restrict__ A, const ushortt* __restrict__ B,
               const float* __restrict__ bias, void* __restrict__ Cout,
               int M, int N, int Kpp, int ldc,
               const float* __restrict__ bias2, float* __restrict__ out2,
               float* __restrict__ out3, float* __restrict__ out4) {
    __shared__ __align__(16) ushortt As[128 * 32];
    __shared__ __align__(16) ushortt Bs[64 * 32];
    const int tid = threadIdx.x;
    const int wid = tid >> 6, lane = tid & 63;
    const int bRow = blockIdx.y * 128, bCol = blockIdx.x * 64;

    float4v acc[2][4];
    const float4v zz = {0.f, 0.f, 0.f, 0.f};
    #pragma unroll
    for (int m = 0; m < 2; ++m)
        #pragma unroll
        for (int n = 0; n < 4; ++n) acc[m][n] = zz;

    const int arow = tid >> 1, acol = (tid & 1) * 16;
    const int brow = tid >> 2, bcol = (tid & 3) * 8;
    const int fr = lane & 15, kg = lane >> 4;

    for (int k0 = 0; k0 < Kpp; k0 += 32) {
        const ushortt* ag = A + (size_t)(bRow + arow) * Kpp + k0 + acol;
        float4v a0 = *(const float4v*)ag;
        float4v a1 = *(const float4v*)(ag + 8);
        const ushortt* bg = B + (size_t)(bCol + brow) * Kpp + k0 + bcol;
        float4v b0 = *(const float4v*)bg;
        __syncthreads();
        *(float4v*)&As[arow * 32 + acol] = a0;
        *(float4v*)&As[arow * 32 + acol + 8] = a1;
        *(float4v*)&Bs[brow * 32 + bcol] = b0;
        __syncthreads();

        short8 bf[4];
        #pragma unroll
        for (int n = 0; n < 4; ++n)
            bf[n] = *(const short8*)&Bs[(n * 16 + fr) * 32 + kg * 8];
        #pragma unroll
        for (int m = 0; m < 2; ++m) {
            short8 af = *(const short8*)&As[(wid * 32 + m * 16 + fr) * 32 + kg * 8];
            #pragma unroll
            for (int n = 0; n < 4; ++n)
                acc[m][n] = __builtin_amdgcn_mfma_f32_16x16x32_bf16(af, bf[n], acc[m][n], 0, 0, 0);
        }
    }

    #pragma unroll
    for (int m = 0; m < 2; ++m)
        #pragma unroll
        for (int n = 0; n < 4; ++n)
            #pragma unroll
            for (int j = 0; j < 4; ++j) {
                const int row = bRow + wid * 32 + m * 16 + (lane >> 4) * 4 + j;
                const int col = bCol + n * 16 + (lane & 15);
                const float v = acc[m][n][j];
                if (EPI == 0) {
                    if (row < M && col < N) ((float*)Cout)[(size_t)row * ldc + col] = v;
                } else if (EPI == 3) {
                    if (row < M && col < 928) {
                        float h = (col < DI) ? fmaxf(v + bias[col], 0.f) : 0.f;
                        ((ushortt*)Cout)[(size_t)row * 928 + col] = f2bf(h);
                    }
                } else if (EPI == 4) {
                    if (row < M && col < N) ((float*)Cout)[(size_t)row * ldc + col] = v + bias[col];
                } else if (EPI == 5) {
                    if (col < H3) {
                        int part = col / 380;
                        int c = col - part * 380;
                        int nh = c / 38, d = c - nh * 38;
                        int q = row >> 2, b2 = row & 3;
                        size_t i40 = (((size_t)b2 * NH + nh) * 1024 + q) * 40 + d;
                        size_t i64 = (((size_t)b2 * NH + nh) * 1024 + q) * 64 + d;
                        if (part == 0) {
                            ((ushortt*)Cout)[i40] = f2bf(v + bias[c]);         // qw_bf (+r_w_bias)
                            ((ushortt*)out2)[i64] = f2bf(v + bias2[c]);        // qr_bf (+r_r_bias)
                        } else if (part == 1) ((ushortt*)out3)[i40] = f2bf(v); // K_bf
                        else ((ushortt*)out4)[i40] = f2bf(v);                  // V_bf
                    }
                } else {  // EPI 6
                    if (row < RLEN && col < DM) {
                        int nh = col / 38, d = col - nh * 38;
                        ((ushortt*)Cout)[((size_t)nh * RLP + row) * 64 + d] = f2bf(v);
                    }
                }
            }
}

// ---------------- BD GEMM: all 10 heads per block, fp8 out, coalesced store -----
// BD: fp8 [lb][1024 q][2052 j][10 n]; 1-D XCD-grouped grid (65 jt share A-panel).
__global__ __launch_bounds__(256)
void bd_gemm(const ushortt* __restrict__ qr, const ushortt* __restrict__ rk,
             uchar* __restrict__ BD, int bofs, int nb) {
    __shared__ __align__(16) ushortt As[64][72];
    __shared__ __align__(16) ushortt Bs[32][72];
    __shared__ __align__(16) uchar Call[64 * 32 * 10];
    const int bid = blockIdx.x;
    const int xcd = bid & 7, t = bid >> 3;
    const int gl = t / 65, jt = t - gl * 65;
    const int G = gl * 8 + xcd;             // 0 .. 16*nb-1
    const int lb = G >> 4, qt = G & 15;
    const int tid = threadIdx.x;
    const int wid = tid >> 6, lane = tid & 63;
    const int j0 = jt * 32, q0 = qt * 64;
    const int fr = lane & 15, kg = lane >> 4;
    const int jcount = min(32, RLEN - j0);

    for (int n = 0; n < NH; ++n) {
        const ushortt* Ab = qr + (((size_t)(bofs + lb) * NH + n) * 1024 + q0) * 64;
        const ushortt* Bb = rk + ((size_t)n * RLP + j0) * 64;
        __syncthreads();
        {
            int rr = tid >> 2, cc = (tid & 3) * 16;
            *(float4v*)&As[rr][cc] = *(const float4v*)(Ab + (size_t)rr * 64 + cc);
            *(float4v*)&As[rr][cc + 8] = *(const float4v*)(Ab + (size_t)rr * 64 + cc + 8);
            int br = tid >> 3, bc = (tid & 7) * 8;
            *(float4v*)&Bs[br][bc] = *(const float4v*)(Bb + (size_t)br * 64 + bc);
        }
        __syncthreads();
        float4v acc[2] = {{0.f,0.f,0.f,0.f},{0.f,0.f,0.f,0.f}};
        #pragma unroll
        for (int ks = 0; ks < 64; ks += 32) {
            short8 af = *(const short8*)&As[wid * 16 + fr][ks + kg * 8];
            #pragma unroll
            for (int c = 0; c < 2; ++c) {
                short8 bfr = *(const short8*)&Bs[c * 16 + fr][ks + kg * 8];
                acc[c] = __builtin_amdgcn_mfma_f32_16x16x32_bf16(af, bfr, acc[c], 0, 0, 0);
            }
        }
        #pragma unroll
        for (int c = 0; c < 2; ++c)
            #pragma unroll
            for (int jj = 0; jj < 4; ++jj) {
                int rq = wid * 16 + (lane >> 4) * 4 + jj;
                int cj = c * 16 + (lane & 15);
                Call[(rq * 32 + cj) * 10 + n] = f2e4m3(acc[c][jj]);
            }
    }
    __syncthreads();
    if (jcount == 32) {
        const unsigned* Cdw = (const unsigned*)Call;
        unsigned* G2 = (unsigned*)BD;
        for (int idx = tid; idx < 64 * 80; idx += 256) {
            int rr = idx / 80, rem = idx - rr * 80;
            size_t gdw = (((size_t)(lb * 1024 + q0 + rr) * RLD + j0) * 10) >> 2;
            G2[gdw + rem] = Cdw[rr * 80 + rem];
        }
    } else {  // tail tile (j0=2048, jcount=1): 10 bytes per row
        for (int idx = tid; idx < 64 * 10; idx += 256) {
            int rr = idx / 10, n2 = idx - rr * 10;
            BD[((size_t)(lb * 1024 + q0 + rr) * RLD + j0) * 10 + n2] = Call[rr * 320 + n2];
        }
    }
}

// ---------------- MFMA-AC split-K fused attention, 32 q-rows per block -------
// qw_bf/K_bf/V_bf bf16 [b][n][1024][40]; BD fp8 [lb][1024 q][2052 j][10]
// LDS 18.6KB -> 8 blocks/CU. Stride-48 tiles (no K=64 zero pad; chunk2 frag
// is (lane>>4)==0 ? cols32..39 : zero). V staged bf16, cvt in PV.
__global__ __launch_bounds__(256)
void attn7(const ushortt* __restrict__ qwb, const ushortt* __restrict__ Kp,
           const ushortt* __restrict__ Vp, const uchar* __restrict__ BD,
           const int* __restrict__ relpos,
           ushortt* __restrict__ op, float2* __restrict__ ml, int b0, int nb) {
    const int bid = blockIdx.x;
    const int xcd = bid & 7, t = bid >> 3;
    const int gl = t / 10, n = t - gl * 10;
    const int G = gl * 8 + xcd;                // 0 .. 80*nb-1, heavy-first
    int qc, lb, s;
    {
        const int c3 = 32 * nb, c2 = 24 * nb, c1 = 16 * nb;
        if (G < c3)                { qc = 31 - G / (4 * nb); int r2 = G % (4 * nb); lb = r2 >> 2; s = r2 & 3; }
        else if (G < c3 + c2)      { int l2 = G - c3; qc = 23 - l2 / (3 * nb); int r2 = l2 % (3 * nb); lb = r2 / 3; s = r2 % 3; }
        else if (G < c3 + c2 + c1) { int l2 = G - c3 - c2; qc = 15 - l2 / (2 * nb); int r2 = l2 % (2 * nb); lb = r2 >> 1; s = r2 & 1; }
        else                       { int l2 = G - c3 - c2 - c1; qc = 7 - l2 / nb; lb = l2 % nb; s = 0; }
    }
    const int ns = (qc >> 3) + 1;
    const int qbase = qc * 32;
    const int b = b0 + lb;
    const int tid = threadIdx.x;
    const int wid = tid >> 6, lane = tid & 63;
    const int row = tid >> 3, kg = tid & 7;
    const int qi = qbase + row;
    const size_t bn = (size_t)b * NH + n;
    const size_t prow = ((size_t)s * (BSZ * NH) + bn) * 1024 + qi;
    const int ntiles = (qbase + 95) >> 6;

    __shared__ __align__(16) ushortt KtL[64 * 48];   // bf16, cols 0..39 valid
    __shared__ __align__(16) ushortt VtL[64 * 40];   // bf16
    __shared__ __align__(16) ushortt qwL[32 * 48];
    __shared__ __align__(16) ushortt sL[32 * 66];    // AC then p, bf16

    const ushortt* Kbase = Kp + bn * 1024 * 40;
    const ushortt* Vbase = Vp + bn * 1024 * 40;
    const int fr = lane & 15;
    const int kg8 = (lane >> 4) * 8;
    const bool kgz = (lane >> 4) == 0;
    const short8 z8 = {0, 0, 0, 0, 0, 0, 0, 0};

    // block-start: stage qwL (32 x 40 bf16, stride 48)
    for (int e = tid; e < 160; e += 256) {
        int rr = e / 5, cc = (e % 5) * 8;
        *(short8*)&qwL[rr * 48 + cc] = *(const short8*)(qwb + (bn * 1024 + qbase + rr) * 40 + cc);
    }
    float o[5] = {0.f, 0.f, 0.f, 0.f, 0.f};
    float mrun = -INFINITY, lrun = 0.f;
    const int* rp = relpos + ((size_t)b * QLEN + qi) * QLEN;
    const uchar* bdrow = BD + ((size_t)(lb * 1024 + qi)) * (RLD * 10) + n;

    for (int kt = s; kt < ntiles; kt += ns) {
        const int k0 = kt * 64;
        __syncthreads();
        // stage K (stride 48) + V (stride 40), raw bf16
        for (int e = tid; e < 320; e += 256) {
            int rr = e / 5, cc = (e % 5) * 8;
            *(short8*)&KtL[rr * 48 + cc] = *(const short8*)(Kbase + (size_t)(k0 + rr) * 40 + cc);
        }
        for (int e = tid; e < 320; e += 256)
            ((short8*)VtL)[e] = ((const short8*)(Vbase + (size_t)k0 * 40))[e];
        __syncthreads();

        // BD gather (issued early; consumed after MFMA barrier)
        int jv[8];
        #pragma unroll
        for (int ss = 0; ss < 8; ++ss) {
            const int kk = k0 + kg + ss * 8;
            int j = -1;
            if (kk <= qi) {
                int rpv = rp[kk];
                rpv = rpv < -1024 ? -1024 : (rpv > 1024 ? 1024 : rpv);
                j = 1024 - rpv;
            }
            jv[ss] = j;
        }
        float bdv[8];
        #pragma unroll
        for (int ss = 0; ss < 8; ++ss)
            bdv[ss] = (jv[ss] >= 0) ? e4m32f(bdrow[(size_t)jv[ss] * 10]) : 0.f;

        // MFMA: AC[32][64] = qw @ K^T  (wave -> (mt, 2 ct tiles))
        {
            const int mt = wid >> 1, ctb = (wid & 1) * 2;
            short8 a0 = *(const short8*)&qwL[(mt * 16 + fr) * 48 + kg8];
            short8 a1 = kgz ? *(const short8*)&qwL[(mt * 16 + fr) * 48 + 32] : z8;
            #pragma unroll
            for (int c = 0; c < 2; ++c) {
                const int ct = ctb + c;
                short8 b0f = *(const short8*)&KtL[(ct * 16 + fr) * 48 + kg8];
                short8 b1f = kgz ? *(const short8*)&KtL[(ct * 16 + fr) * 48 + 32] : z8;
                float4v acc = {0.f, 0.f, 0.f, 0.f};
                acc = __builtin_amdgcn_mfma_f32_16x16x32_bf16(a0, b0f, acc, 0, 0, 0);
                acc = __builtin_amdgcn_mfma_f32_16x16x32_bf16(a1, b1f, acc, 0, 0, 0);
                #pragma unroll
                for (int j = 0; j < 4; ++j)
                    sL[(mt * 16 + (lane >> 4) * 4 + j) * 66 + ct * 16 + fr] = f2bf(acc[j]);
            }
        }
        __syncthreads();

        // score combine + online softmax
        float sarr[8];
        float pmax = -INFINITY;
        #pragma unroll
        for (int ss = 0; ss < 8; ++ss) {
            float sv = -INFINITY;
            if (jv[ss] >= 0)
                sv = (bf2f(sL[row * 66 + kg + ss * 8]) + bdv[ss]) * SCALE;
            sarr[ss] = sv;
            pmax = fmaxf(pmax, sv);
        }
        pmax = fmaxf(pmax, __shfl_xor(pmax, 1, 64));
        pmax = fmaxf(pmax, __shfl_xor(pmax, 2, 64));
        pmax = fmaxf(pmax, __shfl_xor(pmax, 4, 64));
        const float nm = fmaxf(mrun, pmax);
        const float corr = __expf(mrun - nm);   // first tile: exp(-inf)=0
        float psum = 0.f;
        ushortt* prw = sL + row * 66;
        #pragma unroll
        for (int ss = 0; ss < 8; ++ss) {
            float p = __expf(sarr[ss] - nm);
            psum += p;
            prw[kg + ss * 8] = f2bf(p);
        }
        psum += __shfl_xor(psum, 1, 64);
        psum += __shfl_xor(psum, 2, 64);
        psum += __shfl_xor(psum, 4, 64);
        lrun = lrun * corr + psum;
        mrun = nm;
        #pragma unroll
        for (int jj = 0; jj < 5; ++jj) o[jj] *= corr;
        int kmax = qi - k0 + 1; if (kmax > 64) kmax = 64;
        #pragma unroll 4
        for (int k = 0; k < kmax; ++k) {
            float p = bf2f(prw[k]);
            const ushortt* vr = VtL + k * 40;
            uint2 v4u = *(const uint2*)(vr + 4 * kg);
            o[0] += p * bf2f((ushortt)(v4u.x & 0xffff));
            o[1] += p * bf2f((ushortt)(v4u.x >> 16));
            o[2] += p * bf2f((ushortt)(v4u.y & 0xffff));
            o[3] += p * bf2f((ushortt)(v4u.y >> 16));
            o[4] += p * bf2f(vr[32 + kg]);
        }
    }
    ushortt* oprow = op + prow * 40;
    #pragma unroll
    for (int jj = 0; jj < 4; ++jj) oprow[4 * kg + jj] = f2bf(o[jj]);
    oprow[32 + kg] = f2bf(o[4]);
    if (kg == 0) ml[prow] = make_float2(mrun, lrun);
}

// ---------------- combine split partials -> vec (bf16) ----------------
__global__ __launch_bounds__(256)
void attn_combine(const ushortt* __restrict__ op, const float2* __restrict__ ml,
                  ushortt* __restrict__ vec) {
    const int idx = blockIdx.x * 256 + threadIdx.x;
    if (idx >= BSZ * NH * 1024 * 38) return;
    const int d = idx % 38;
    const int rh = idx / 38;                 // bn*1024 + q
    const int q = rh & 1023;
    const int bn = rh >> 10;
    const int b = bn / NH, n = bn - b * NH;
    const int ns = ((q >> 5) >> 3) + 1;      // splits for this q's chunk
    const size_t stride = (size_t)BSZ * NH * 1024;
    float M = -INFINITY;
    float2 mv[4];
    for (int sp = 0; sp < ns; ++sp) {
        mv[sp] = ml[sp * stride + rh];
        M = fmaxf(M, mv[sp].x);
    }
    float l = 0.f, o = 0.f;
    for (int sp = 0; sp < ns; ++sp) {
        float w = __expf(mv[sp].x - M);
        l += mv[sp].y * w;
        o += bf2f(op[(sp * stride + rh) * 40 + d]) * w;
    }
    vec[((size_t)q * BSZ + b) * 384 + (size_t)n * 38 + d] = f2bf(o / l);
}

// ---------------- residual + LayerNorm ----------------
template<bool WRITE_BF>
__global__ __launch_bounds__(256)
void ln_kernel(const float* __restrict__ x1, const float* __restrict__ x2,
               const float* __restrict__ g, const float* __restrict__ bb,
               float* __restrict__ outf, ushortt* __restrict__ outbf) {
    const int row = blockIdx.x;
    const float* p1 = x1 + (size_t)row * DM;
    const float* p2 = x2 + (size_t)row * DM;
    __shared__ float xb[DM];
    __shared__ float red[256];
    const int tid = threadIdx.x;
    float s = 0.f;
    for (int i = tid; i < DM; i += 256) { float v = p1[i] + p2[i]; xb[i] = v; s += v; }
    red[tid] = s; __syncthreads();
    for (int st = 128; st > 0; st >>= 1) { if (tid < st) red[tid] += red[tid + st]; __syncthreads(); }
    const float mean = red[0] / DM;
    __syncthreads();
    float s2 = 0.f;
    for (int i = tid; i < DM; i += 256) { float d = xb[i] - mean; s2 += d * d; }
    red[tid] = s2; __syncthreads();
    for (int st = 128; st > 0; st >>= 1) { if (tid < st) red[tid] += red[tid + st]; __syncthreads(); }
    const float rstd = rsqrtf(red[0] / DM + 1e-5f);
    for (int i = tid; i < (WRITE_BF ? 384 : DM); i += 256) {
        float v = 0.f;
        if (i < DM) {
            v = (xb[i] - mean) * rstd * g[i] + bb[i];
            outf[(size_t)row * DM + i] = v;
        }
        if (WRITE_BF) outbf[(size_t)row * 384 + i] = f2bf(i < DM ? v : 0.f);
    }
}

extern "C" void kernel_launch(void* const* d_in, const int* in_sizes, int n_in,
                              void* d_out, int out_size, void* d_ws, size_t ws_size,
                              hipStream_t stream) {
    const float* w     = (const float*)d_in[0];
    const float* r     = (const float*)d_in[1];
    const float* rwb   = (const float*)d_in[2];
    const float* rrb   = (const float*)d_in[3];
    const float* qkv_w = (const float*)d_in[4];
    const float* r_w   = (const float*)d_in[5];
    const float* o_w   = (const float*)d_in[6];
    const float* ln1g  = (const float*)d_in[7];
    const float* ln1b  = (const float*)d_in[8];
    const float* ffw1  = (const float*)d_in[9];
    const float* ffb1  = (const float*)d_in[10];
    const float* ffw2  = (const float*)d_in[11];
    const float* ffb2  = (const float*)d_in[12];
    const float* ln2g  = (const float*)d_in[13];
    const float* ln2b  = (const float*)d_in[14];
    const int*   relpos = (const int*)d_in[16];
    float* out = (float*)d_out;

    char* cur = (char*)d_ws;
    auto alloc = [&](size_t bytes) { char* p = cur; cur += (bytes + 255) & ~(size_t)255; return p; };
    ushortt* w_bf    = (ushortt*)alloc((size_t)4096 * 384 * 2);
    ushortt* qkv_bf  = (ushortt*)alloc((size_t)1152 * 384 * 2);
    ushortt* r_bf    = (ushortt*)alloc((size_t)2176 * 384 * 2);
    ushortt* rw_bf   = (ushortt*)alloc((size_t)384 * 384 * 2);
    ushortt* ow_bf   = (ushortt*)alloc((size_t)384 * 384 * 2);
    ushortt* f1_bf   = (ushortt*)alloc((size_t)960 * 384 * 2);
    ushortt* f2_bf   = (ushortt*)alloc((size_t)384 * 928 * 2);
    ushortt* qw_bf   = (ushortt*)alloc((size_t)BSZ * NH * 1024 * 40 * 2);
    ushortt* K_bf    = (ushortt*)alloc((size_t)BSZ * NH * 1024 * 40 * 2);
    ushortt* V_bf    = (ushortt*)alloc((size_t)BSZ * NH * 1024 * 40 * 2);
    ushortt* qr_bf   = (ushortt*)alloc((size_t)BSZ * NH * 1024 * 64 * 2);
    ushortt* rk_bf   = (ushortt*)alloc((size_t)NH * RLP * 64 * 2);
    ushortt* vec_bf  = (ushortt*)alloc((size_t)4096 * 384 * 2);
    ushortt* out1_bf = (ushortt*)alloc((size_t)4096 * 384 * 2);
    ushortt* h1_bf   = (ushortt*)alloc((size_t)4096 * 928 * 2);
    float*   attnf   = (float*)alloc((size_t)4096 * DM * 4);
    float*   out1f   = (float*)alloc((size_t)4096 * DM * 4);
    float*   core    = (float*)alloc((size_t)4096 * DM * 4);

    // split partials alias attnf/out1f/core (dead until after combine):
    ushortt* op_part = (ushortt*)attnf;
    float2*  ml_part = (float2*)((char*)attnf + (size_t)4 * BSZ * NH * 1024 * 40 * 2);

    // BD buffer: fp8 [lb][1024 q][2052 j][10]
    const size_t bd_b_bytes = (size_t)1024 * RLD * 10;   // per-b: ~21 MB
    uchar* BD = (uchar*)alloc(bd_b_bytes * BSZ);
    bool full = ((size_t)(cur - (char*)d_ws) <= ws_size);
    if (!full) { cur = (char*)BD; BD = (uchar*)alloc(bd_b_bytes); }  // per-b reuse

    auto cgrid = [](size_t total) { return dim3((unsigned)((total + 255) / 256)); };
    // fused prologue: all conversions + all pad zeroing, one launch
    prep_all<<<dim3(2048), 256, 0, stream>>>(w, w_bf, qkv_w, qkv_bf, r, r_bf,
                                             r_w, rw_bf, o_w, ow_bf, ffw1, f1_bf, ffw2, f2_bf,
                                             qw_bf, K_bf, V_bf, qr_bf, rk_bf, vec_bf);

    // QKV GEMM with scatter epilogue -> qw_bf / qr_bf / K_bf / V_bf
    gemm_mfma<5><<<dim3(18, 32), 256, 0, stream>>>(w_bf, qkv_bf, rwb, qw_bf, 4096, H3, 384, 0,
                                                   rrb, (float*)qr_bf, (float*)K_bf, (float*)V_bf);
    // rk GEMM -> rk_bf  bf16 [n][2112][64]
    gemm_mfma<6><<<dim3(6, 17), 256, 0, stream>>>(r_bf, rw_bf, nullptr, rk_bf, RLEN, DM, 384, 0,
                                                  nullptr, nullptr, nullptr, nullptr);
    if (full) {
        bd_gemm<<<dim3(65 * 16 * BSZ), 256, 0, stream>>>(qr_bf, rk_bf, BD, 0, BSZ);
        attn7<<<dim3(3200), 256, 0, stream>>>(qw_bf, K_bf, V_bf, BD, relpos,
                                              op_part, ml_part, 0, BSZ);
    } else {
        for (int b = 0; b < BSZ; ++b) {
            bd_gemm<<<dim3(65 * 16), 256, 0, stream>>>(qr_bf, rk_bf, BD, b, 1);
            attn7<<<dim3(800), 256, 0, stream>>>(qw_bf, K_bf, V_bf, BD, relpos,
                                                 op_part, ml_part, b, 1);
        }
    }
    attn_combine<<<cgrid((size_t)BSZ * NH * 1024 * 38), 256, 0, stream>>>(op_part, ml_part, vec_bf);
    // attn_out = vec @ o_w^T   (overwrites op_part alias -- partials are dead)
    gemm_mfma<0><<<dim3(6, 32), 256, 0, stream>>>(vec_bf, ow_bf, nullptr, attnf, 4096, DM, 384, DM,
                                                  nullptr, nullptr, nullptr, nullptr);
    ln_kernel<true><<<4096, 256, 0, stream>>>(w, attnf, ln1g, ln1b, out1f, out1_bf);
    gemm_mfma<3><<<dim3(15, 32), 256, 0, stream>>>(out1_bf, f1_bf, ffb1, h1_bf, 4096, DI, 384, 928,
                                                   nullptr, nullptr, nullptr, nullptr);
    gemm_mfma<4><<<dim3(6, 32), 256, 0, stream>>>(h1_bf, f2_bf, ffb2, core, 4096, DM, 928, DM,
                                                  nullptr, nullptr, nullptr, nullptr);
    ln_kernel<false><<<4096, 256, 0, stream>>>(out1f, core, ln2g, ln2b, out, nullptr);
}